// Round 2
// baseline (874.545 us; speedup 1.0000x reference)
//
#include <hip/hip_runtime.h>

#define NNODES 50000
#define RREL 51
#define FIN 32
#define EDIM 32
#define CDIM 16
#define BB 30
#define NNZ_ 2000000

typedef unsigned int uint32;

// ---------- bf16 pack/unpack (manual RNE, no header dependency) ----------
static __device__ __forceinline__ uint32 pack_bf16x2(float a, float b) {
    uint32 ua = __builtin_bit_cast(uint32, a);
    uint32 ub = __builtin_bit_cast(uint32, b);
    ua += 0x7fffu + ((ua >> 16) & 1u);
    ub += 0x7fffu + ((ub >> 16) & 1u);
    return (ua >> 16) | (ub & 0xffff0000u);
}
static __device__ __forceinline__ float2 unpack_bf16x2(uint32 u) {
    float2 f;
    f.x = __builtin_bit_cast(float, u << 16);
    f.y = __builtin_bit_cast(float, u & 0xffff0000u);
    return f;
}

// ---------------- weight build: w[r] = sum_b comps[r,b] * bases[b] ----------------
__global__ void k_weights(const float* __restrict__ comps1, const float* __restrict__ bases1,
                          const float* __restrict__ comps2, const float* __restrict__ bases2,
                          float* __restrict__ w1, float* __restrict__ w2) {
    int i = blockIdx.x * 256 + threadIdx.x;
    if (i < RREL * FIN * EDIM) {          // (R, F, E)
        int r = i >> 10, fe = i & 1023;
        float acc = 0.f;
#pragma unroll
        for (int b = 0; b < BB; b++) acc += comps1[r * BB + b] * bases1[b * 1024 + fe];
        w1[i] = acc;
    }
    if (i < RREL * EDIM * CDIM) {         // (R, E, C)
        int r = i >> 9, ec = i & 511;
        float acc = 0.f;
#pragma unroll
        for (int b = 0; b < BB; b++) acc += comps2[r * BB + b] * bases2[b * 512 + ec];
        w2[i] = acc;
    }
}

// ---------------- histograms: per-relation (LDS) + per-dst (global) ----------------
__global__ void k_hist(const int* __restrict__ rows, int* __restrict__ rel_cnt,
                       int* __restrict__ dst_cnt) {
    __shared__ int lc[RREL];
    if (threadIdx.x < RREL) lc[threadIdx.x] = 0;
    __syncthreads();
    int stride = gridDim.x * blockDim.x;
    for (int k = blockIdx.x * blockDim.x + threadIdx.x; k < NNZ_; k += stride) {
        int rw = rows[k];
        int rel = rw / NNODES;
        atomicAdd(&lc[rel], 1);
        atomicAdd(&dst_cnt[rw - rel * NNODES], 1);
    }
    __syncthreads();
    if (threadIdx.x < RREL) atomicAdd(&rel_cnt[threadIdx.x], lc[threadIdx.x]);
}

__global__ void k_prefix(const int* __restrict__ rel_cnt, int* __restrict__ rel_base) {
    if (threadIdx.x == 0) {
        int acc = 0;
        for (int r = 0; r < RREL; r++) { rel_base[r] = acc; acc += rel_cnt[r]; }
    }
}

// exclusive prefix over NNODES entries -> dst_base[0..NNODES]
__global__ __launch_bounds__(1024) void k_scan_dst(const int* __restrict__ cnt,
                                                   int* __restrict__ base) {
    __shared__ int ssum[1024];
    int t = threadIdx.x;
    const int CH = (NNODES + 1023) / 1024;   // 49
    int lo = t * CH, hi = min(lo + CH, NNODES);
    int s = 0;
    for (int i = lo; i < hi; i++) s += cnt[i];
    ssum[t] = s;
    __syncthreads();
    for (int off = 1; off < 1024; off <<= 1) {
        int v = (t >= off) ? ssum[t - off] : 0;
        __syncthreads();
        ssum[t] += v;
        __syncthreads();
    }
    int run = (t == 0) ? 0 : ssum[t - 1];
    for (int i = lo; i < hi; i++) { base[i] = run; run += cnt[i]; }
    if (t == 1023) base[NNODES] = run;
}

// ---------------- counting sort by relation + dst-rank assignment ----------------
__global__ void k_scatter(const int* __restrict__ rows, const int* __restrict__ cols,
                          const float* __restrict__ vals, int* __restrict__ rel_base,
                          const int* __restrict__ dst_base, int* __restrict__ dst_cur,
                          int* __restrict__ s_key, int* __restrict__ s_pos,
                          int* __restrict__ s_src, float* __restrict__ s_val) {
    __shared__ int lcnt[RREL], lbase[RREL];
    int t = threadIdx.x;
    int base = blockIdx.x * 2048;
    if (t < RREL) lcnt[t] = 0;
    __syncthreads();
    int relv[8];
#pragma unroll
    for (int i = 0; i < 8; i++) {
        int k = base + i * 256 + t;
        if (k < NNZ_) { int r = rows[k] / NNODES; relv[i] = r; atomicAdd(&lcnt[r], 1); }
        else relv[i] = -1;
    }
    __syncthreads();
    if (t < RREL) lbase[t] = atomicAdd(&rel_base[t], lcnt[t]);
    __syncthreads();
    if (t < RREL) lcnt[t] = 0;
    __syncthreads();
#pragma unroll
    for (int i = 0; i < 8; i++) {
        int k = base + i * 256 + t;
        if (k < NNZ_) {
            int r = relv[i];
            int rw = rows[k];
            int dst = rw - r * NNODES;
            int pos = lbase[r] + atomicAdd(&lcnt[r], 1);
            int p = dst_base[dst] + atomicAdd(&dst_cur[dst], 1);
            s_key[pos] = (r << 16) | dst;
            s_pos[pos] = p;
            s_src[pos] = cols[k];
            s_val[pos] = vals[k];
        }
    }
}

// ---------------- per-edge matvec helper ----------------
template <int FO>
__device__ __forceinline__ void matvec_acc(const float* __restrict__ wb,
                                           const float (&xr)[32], float (&acc)[FO]) {
#pragma unroll
    for (int f = 0; f < 32; f++) {
        float xf = xr[f];
#pragma unroll
        for (int e = 0; e < FO; e++) acc[e] = fmaf(xf, wb[f * FO + e], acc[e]);
    }
}

// ---------------- stage A: y[p] = bf16( val * (X[src] @ W[rel]) ), plain stores ----------
template <int FO>
__global__ __launch_bounds__(256) void k_edgeA(const int* __restrict__ s_key,
                                               const int* __restrict__ s_pos,
                                               const int* __restrict__ s_src,
                                               const float* __restrict__ s_val,
                                               const float* __restrict__ X,
                                               const float* __restrict__ W,
                                               uint32* __restrict__ y) {
    const int UPR = FO / 2;                      // uints per row: 16 (FO=32) / 8 (FO=16)
    const int STRIDE = (FO == 32) ? 66 : 69;     // <=2-way LDS aliasing (free) both phases
    __shared__ uint32 Yt[4][UPR][STRIDE];
    __shared__ int P[4][64];
    int t = threadIdx.x;
    int lane = t & 63, wv = t >> 6;
    int k = blockIdx.x * 256 + t;
    int key = 0, src = 0, p = -1;
    float v = 0.f;
    if (k < NNZ_) { key = s_key[k]; src = s_src[k]; v = s_val[k]; p = s_pos[k]; }
    int rel = key >> 16;

    float xr[32];
    const float4* xp = (const float4*)X + src * 8;
#pragma unroll
    for (int i = 0; i < 8; i++) {
        float4 q = xp[i];
        xr[4 * i] = q.x; xr[4 * i + 1] = q.y; xr[4 * i + 2] = q.z; xr[4 * i + 3] = q.w;
    }
    float acc[FO];
#pragma unroll
    for (int e = 0; e < FO; e++) acc[e] = 0.f;

    int rel_u = __builtin_amdgcn_readfirstlane(rel);
    if (__all(rel == rel_u)) {
        matvec_acc<FO>(W + rel_u * (32 * FO), xr, acc);   // uniform -> scalar loads
    } else {
        matvec_acc<FO>(W + rel * (32 * FO), xr, acc);     // rel-boundary waves (rare)
    }

    // transpose via LDS (same-wave only; compiler inserts lgkmcnt, no barrier needed)
#pragma unroll
    for (int i = 0; i < UPR; i++)
        Yt[wv][i][lane] = pack_bf16x2(v * acc[2 * i], v * acc[2 * i + 1]);
    P[wv][lane] = p;

    const int EPI = 64 / UPR;      // edges per store instruction
    int u = lane % UPR;
    int g = lane / UPR;
#pragma unroll
    for (int j = 0; j < UPR; j++) {
        int e = j * EPI + g;
        int pe = P[wv][e];
        uint32 val = Yt[wv][u][e];
        if (pe >= 0) y[(size_t)pe * UPR + u] = val;
    }
}

// ---------------- stage B: segmented sum over dst-sorted y, fused bias(+relu) ----------
template <int FO, bool RELU>
__global__ __launch_bounds__(256) void k_segB(const uint32* __restrict__ y,
                                              const int* __restrict__ dst_base,
                                              const float* __restrict__ bias,
                                              float* __restrict__ out) {
    const int UPR = FO / 2;
    const int RPI = 64 / UPR;      // rows per iteration
    int t = threadIdx.x, lane = t & 63, wv = t >> 6;
    int dst = blockIdx.x * 4 + wv;
    if (dst >= NNODES) return;
    int s = dst_base[dst], e = dst_base[dst + 1];
    int f2 = lane % UPR;
    int sub = lane / UPR;
    float2 acc = make_float2(0.f, 0.f);
    for (int i = s + sub; i < e; i += RPI) {
        float2 f = unpack_bf16x2(y[(size_t)i * UPR + f2]);
        acc.x += f.x; acc.y += f.y;
    }
#pragma unroll
    for (int off = 32; off >= UPR; off >>= 1) {
        acc.x += __shfl_down(acc.x, off, 64);
        acc.y += __shfl_down(acc.y, off, 64);
    }
    if (lane < UPR) {
        float ox = acc.x + bias[2 * f2];
        float oy = acc.y + bias[2 * f2 + 1];
        if (RELU) { ox = fmaxf(ox, 0.f); oy = fmaxf(oy, 0.f); }
        ((float2*)out)[(size_t)dst * UPR + f2] = make_float2(ox, oy);
    }
}

// ---------------- fallback: atomic edge kernel (round-1 path) ----------------
template <int FO>
__global__ __launch_bounds__(256) void k_edge(const int* __restrict__ s_key,
                                              const int* __restrict__ s_src,
                                              const float* __restrict__ s_val,
                                              const float* __restrict__ X,
                                              const float* __restrict__ W,
                                              float* __restrict__ out) {
    __shared__ float Y[4][64 * (FO + 1)];
    __shared__ int D[4][64];
    int t = threadIdx.x;
    int lane = t & 63, wv = t >> 6;
    int k = blockIdx.x * 256 + t;
    int key = 0, src = 0;
    float v = 0.f;
    if (k < NNZ_) { key = s_key[k]; src = s_src[k]; v = s_val[k]; }
    int rel = key >> 16, dst = key & 0xffff;

    float xr[32];
    const float4* xp = (const float4*)X + src * 8;
#pragma unroll
    for (int i = 0; i < 8; i++) {
        float4 q = xp[i];
        xr[4 * i] = q.x; xr[4 * i + 1] = q.y; xr[4 * i + 2] = q.z; xr[4 * i + 3] = q.w;
    }
    float acc[FO];
#pragma unroll
    for (int e = 0; e < FO; e++) acc[e] = 0.f;

    int rel_u = __builtin_amdgcn_readfirstlane(rel);
    if (__all(rel == rel_u)) matvec_acc<FO>(W + rel_u * (32 * FO), xr, acc);
    else matvec_acc<FO>(W + rel * (32 * FO), xr, acc);

    float* yy = &Y[wv][0];
#pragma unroll
    for (int e = 0; e < FO; e++) yy[lane * (FO + 1) + e] = v * acc[e];
    D[wv][lane] = dst;
    __syncthreads();

    const int GP = 64 / FO;
    int e = lane & (FO - 1);
    int g = lane / FO;
#pragma unroll
    for (int j = 0; j < FO; j++) {
        int edge = j * GP + g;
        float val = yy[edge * (FO + 1) + e];
        int d = D[wv][edge];
        atomicAdd(&out[d * FO + e], val);
    }
}

__global__ void k_relu(float* __restrict__ h1, const float* __restrict__ bias1) {
    int i = blockIdx.x * 256 + threadIdx.x;
    if (i >= NNODES * EDIM / 4) return;
    float4 v = ((float4*)h1)[i];
    float4 b = ((const float4*)bias1)[i & 7];
    v.x = fmaxf(v.x + b.x, 0.f);
    v.y = fmaxf(v.y + b.y, 0.f);
    v.z = fmaxf(v.z + b.z, 0.f);
    v.w = fmaxf(v.w + b.w, 0.f);
    ((float4*)h1)[i] = v;
}

__global__ void k_out(const float* __restrict__ h2, const float* __restrict__ bias2,
                      float* __restrict__ out) {
    int i = blockIdx.x * 256 + threadIdx.x;
    if (i >= NNODES * CDIM / 4) return;
    float4 v = ((const float4*)h2)[i];
    float4 b = ((const float4*)bias2)[i & 3];
    v.x += b.x; v.y += b.y; v.z += b.z; v.w += b.w;
    ((float4*)out)[i] = v;
}

extern "C" void kernel_launch(void* const* d_in, const int* in_sizes, int n_in,
                              void* d_out, int out_size, void* d_ws, size_t ws_size,
                              hipStream_t stream) {
    const float* features = (const float*)d_in[0];
    const float* vals     = (const float*)d_in[1];
    const float* comps1   = (const float*)d_in[2];
    const float* bases1   = (const float*)d_in[3];
    const float* bias1    = (const float*)d_in[4];
    const float* comps2   = (const float*)d_in[5];
    const float* bases2   = (const float*)d_in[6];
    const float* bias2    = (const float*)d_in[7];
    const int*   rows     = (const int*)d_in[8];
    const int*   cols     = (const int*)d_in[9];
    float* out = (float*)d_out;

    // ---- workspace layout (element offsets in 4-byte units) ----
    float* ws = (float*)d_ws;
    size_t o = 0;
    float* w1 = ws + o;       o += RREL * FIN * EDIM;       // 52224
    float* w2 = ws + o;       o += RREL * EDIM * CDIM;      // 26112
    float* h1 = ws + o;       o += (size_t)NNODES * EDIM;   // 1.6M
    float* h2 = ws + o;       o += (size_t)NNODES * CDIM;   // 0.8M
    int* s_key = (int*)(ws + o); o += NNZ_;
    int* s_pos = (int*)(ws + o); o += NNZ_;
    int* s_src = (int*)(ws + o); o += NNZ_;
    float* s_val = ws + o;       o += NNZ_;
    int* rel_cnt  = (int*)(ws + o); o += RREL;
    int* rel_base = (int*)(ws + o); o += RREL;
    int* dst_cnt  = (int*)(ws + o); o += NNODES;
    int* dst_cur  = (int*)(ws + o); o += NNODES;
    int* dst_base = (int*)(ws + o); o += NNODES + 1;
    o = (o + 3) & ~(size_t)3;
    uint32* y = (uint32*)(ws + o);
    size_t need = (o + (size_t)NNZ_ * (EDIM / 2)) * 4;      // y reused for both layers
    bool fast = ws_size >= need;

    // zero the counter region (rel_cnt .. dst_cur, contiguous)
    hipMemsetAsync(rel_cnt, 0, (2 * RREL + 2 * NNODES) * sizeof(int), stream);

    k_weights<<<(RREL * FIN * EDIM + 255) / 256, 256, 0, stream>>>(comps1, bases1, comps2, bases2, w1, w2);
    k_hist<<<512, 256, 0, stream>>>(rows, rel_cnt, dst_cnt);
    k_prefix<<<1, 64, 0, stream>>>(rel_cnt, rel_base);
    k_scan_dst<<<1, 1024, 0, stream>>>(dst_cnt, dst_base);
    k_scatter<<<(NNZ_ + 2047) / 2048, 256, 0, stream>>>(rows, cols, vals, rel_base, dst_base,
                                                        dst_cur, s_key, s_pos, s_src, s_val);

    if (fast) {
        k_edgeA<EDIM><<<(NNZ_ + 255) / 256, 256, 0, stream>>>(s_key, s_pos, s_src, s_val, features, w1, y);
        k_segB<EDIM, true><<<(NNODES + 3) / 4, 256, 0, stream>>>(y, dst_base, bias1, h1);
        k_edgeA<CDIM><<<(NNZ_ + 255) / 256, 256, 0, stream>>>(s_key, s_pos, s_src, s_val, h1, w2, y);
        k_segB<CDIM, false><<<(NNODES + 3) / 4, 256, 0, stream>>>(y, dst_base, bias2, out);
    } else {
        hipMemsetAsync(h1, 0, (size_t)(NNODES * EDIM + NNODES * CDIM) * sizeof(float), stream);
        k_edge<EDIM><<<(NNZ_ + 255) / 256, 256, 0, stream>>>(s_key, s_src, s_val, features, w1, h1);
        k_relu<<<(NNODES * EDIM / 4 + 255) / 256, 256, 0, stream>>>(h1, bias1);
        k_edge<CDIM><<<(NNZ_ + 255) / 256, 256, 0, stream>>>(s_key, s_src, s_val, h1, w2, h2);
        k_out<<<(NNODES * CDIM / 4 + 255) / 256, 256, 0, stream>>>(h2, bias2, out);
    }
}